// Round 1
// baseline (682.709 us; speedup 1.0000x reference)
//
#include <hip/hip_runtime.h>
#include <cstdint>
#include <cstddef>

// Problem: C[4096,4096] = sum_r input[r] @ weight[r]^T
// input  fp32 [8,4096,1024], weight fp32 [8,4096,1024]
// => single GEMM M=4096, N=4096, K=8192 (K = r*1024 + k_local), fp32 out.
//
// Phase 1: fp32 -> bf16 convert + permute into d_ws as A[M,K], B[N,K] row-major.
// Phase 2: m97-recipe bf16 MFMA GEMM (128x128 tile, BK=64, global_load_lds w=16).

#define M_DIM 4096
#define N_DIM 4096
#define K_DIM 8192
#define K_LOCAL 1024

typedef __bf16 bf16x8 __attribute__((ext_vector_type(8)));
typedef float f32x4 __attribute__((ext_vector_type(4)));

__device__ __forceinline__ unsigned short f2bf(float f) {
    unsigned int u = __float_as_uint(f);
    unsigned int r = (u + 0x7fffu + ((u >> 16) & 1u)) >> 16;
    return (unsigned short)r;
}

// ---------- Phase 1: convert + permute ----------
// dst[m][r*1024 + k] = (bf16) src[r][m][k]
__global__ __launch_bounds__(256) void convert_permute(
    const float* __restrict__ src, unsigned short* __restrict__ dst) {
    size_t t = (size_t)blockIdx.x * 256 + threadIdx.x;
    size_t e = t * 4;  // flat element index in [R, M, K_LOCAL]
    int r = (int)(e >> 22);            // / (4096*1024)
    int rem = (int)(e & 0x3FFFFFu);
    int m = rem >> 10;
    int k = rem & 1023;
    float4 v = *(const float4*)(src + e);
    ushort4 o;
    o.x = f2bf(v.x); o.y = f2bf(v.y); o.z = f2bf(v.z); o.w = f2bf(v.w);
    *(ushort4*)(dst + (size_t)m * K_DIM + r * K_LOCAL + k) = o;
}

// ---------- Phase 2: bf16 MFMA GEMM ----------
__device__ __forceinline__ void async_copy16(const unsigned short* g, unsigned short* l) {
    __builtin_amdgcn_global_load_lds(
        (const __attribute__((address_space(1))) void*)g,
        (__attribute__((address_space(3))) void*)l,
        16, 0, 0);
}

__global__ __launch_bounds__(256) void gemm_bf16(
    const unsigned short* __restrict__ A,  // [M, K] bf16
    const unsigned short* __restrict__ B,  // [N, K] bf16
    float* __restrict__ C) {               // [M, N] fp32
    __shared__ __align__(16) unsigned short As[128 * 64];
    __shared__ __align__(16) unsigned short Bs[128 * 64];

    const int tid = threadIdx.x;
    const int lane = tid & 63;
    const int wave = tid >> 6;
    const int wm = (wave >> 1) * 64;   // wave row offset in 128x128 tile
    const int wn = (wave & 1) * 64;    // wave col offset
    const int l15 = lane & 15;
    const int l4 = lane >> 4;
    const int bm0 = blockIdx.y * 128;
    const int bn0 = blockIdx.x * 128;

    // staging pointers: chunk cc = p*256 + tid covers (row = cc>>3, col8 = cc&7)
    const unsigned short* ga[4];
    const unsigned short* gb[4];
    int lo[4];
#pragma unroll
    for (int p = 0; p < 4; ++p) {
        int cc = p * 256 + tid;
        int row = cc >> 3;
        int col = (cc & 7) * 8;
        ga[p] = A + (size_t)(bm0 + row) * K_DIM + col;
        gb[p] = B + (size_t)(bn0 + row) * K_DIM + col;
        lo[p] = cc * 8;
    }

    const int a_base = (wm + l15) * 64 + l4 * 8;
    const int b_base = (wn + l15) * 64 + l4 * 8;

    f32x4 acc[4][4] = {};

    for (int kt = 0; kt < K_DIM; kt += 64) {
#pragma unroll
        for (int p = 0; p < 4; ++p) {
            async_copy16(ga[p] + kt, &As[lo[p]]);
            async_copy16(gb[p] + kt, &Bs[lo[p]]);
        }
        __syncthreads();
#pragma unroll
        for (int ks = 0; ks < 2; ++ks) {
            bf16x8 af[4], bfr[4];
#pragma unroll
            for (int i = 0; i < 4; ++i)
                af[i] = *(const bf16x8*)&As[a_base + i * 16 * 64 + ks * 32];
#pragma unroll
            for (int j = 0; j < 4; ++j)
                bfr[j] = *(const bf16x8*)&Bs[b_base + j * 16 * 64 + ks * 32];
#pragma unroll
            for (int i = 0; i < 4; ++i)
#pragma unroll
                for (int j = 0; j < 4; ++j)
                    acc[i][j] = __builtin_amdgcn_mfma_f32_16x16x32_bf16(
                        af[i], bfr[j], acc[i][j], 0, 0, 0);
        }
        __syncthreads();
    }

    // epilogue: C/D layout col = lane&15, row = (lane>>4)*4 + reg
#pragma unroll
    for (int i = 0; i < 4; ++i) {
        int row0 = bm0 + wm + i * 16 + l4 * 4;
#pragma unroll
        for (int j = 0; j < 4; ++j) {
            int col = bn0 + wn + j * 16 + l15;
#pragma unroll
            for (int r = 0; r < 4; ++r)
                C[(size_t)(row0 + r) * N_DIM + col] = acc[i][j][r];
        }
    }
}

// ---------- Fallback (ws too small): naive fp32 tiled GEMM on original layout ----------
__global__ void gemm_naive(const float* __restrict__ A, const float* __restrict__ B,
                           float* __restrict__ C) {
    __shared__ float As[16][17];
    __shared__ float Bs[16][17];
    int tx = threadIdx.x, ty = threadIdx.y;
    int m = blockIdx.y * 16 + ty;
    int n0 = blockIdx.x * 16;
    float accv = 0.f;
    for (int kt = 0; kt < K_DIM; kt += 16) {
        int r = kt >> 10;
        int k = (kt & 1023) + tx;
        As[ty][tx] = A[((size_t)r * M_DIM + m) * K_LOCAL + k];
        Bs[ty][tx] = B[((size_t)r * N_DIM + (n0 + ty)) * K_LOCAL + k];
        __syncthreads();
#pragma unroll
        for (int kk = 0; kk < 16; ++kk) accv += As[ty][kk] * Bs[tx][kk];
        __syncthreads();
    }
    C[(size_t)m * N_DIM + n0 + tx] = accv;
}

extern "C" void kernel_launch(void* const* d_in, const int* in_sizes, int n_in,
                              void* d_out, int out_size, void* d_ws, size_t ws_size,
                              hipStream_t stream) {
    const float* inp = (const float*)d_in[0];
    const float* wgt = (const float*)d_in[1];
    float* out = (float*)d_out;

    const size_t elems = (size_t)M_DIM * K_DIM;           // 33,554,432 per tensor
    const size_t need = 2 * elems * sizeof(unsigned short); // 128 MiB

    if (ws_size >= need) {
        unsigned short* Abf = (unsigned short*)d_ws;
        unsigned short* Bbf = Abf + elems;
        const int conv_blocks = (int)(elems / 4 / 256);   // 32768
        convert_permute<<<conv_blocks, 256, 0, stream>>>(inp, Abf);
        convert_permute<<<conv_blocks, 256, 0, stream>>>(wgt, Bbf);
        dim3 grid(N_DIM / 128, M_DIM / 128);              // 32 x 32
        gemm_bf16<<<grid, 256, 0, stream>>>(Abf, Bbf, out);
    } else {
        dim3 grid(N_DIM / 16, M_DIM / 16);
        dim3 block(16, 16);
        gemm_naive<<<grid, block, 0, stream>>>(inp, wgt, out);
    }
}

// Round 2
// 620.741 us; speedup vs baseline: 1.0998x; 1.0998x over previous
//
#include <hip/hip_runtime.h>
#include <cstdint>
#include <cstddef>

// C[4096,4096] = sum_r input[r] @ weight[r]^T  == GEMM M=N=4096, K=8192, fp32 out.
// Phase 1: fp32 -> bf16 convert+permute into d_ws: A[M,K], B[N,K] row-major.
// Phase 2: m97-recipe bf16 MFMA GEMM (128x128 tile, BK=64, global_load_lds w=16)
//          + XOR bank swizzle on the LDS layout (R2: kills the 16-way conflict).

#define M_DIM 4096
#define N_DIM 4096
#define K_DIM 8192
#define K_LOCAL 1024

typedef __bf16 bf16x8 __attribute__((ext_vector_type(8)));
typedef float f32x4 __attribute__((ext_vector_type(4)));

__device__ __forceinline__ unsigned short f2bf(float f) {
    unsigned int u = __float_as_uint(f);
    unsigned int r = (u + 0x7fffu + ((u >> 16) & 1u)) >> 16;
    return (unsigned short)r;
}

// ---------- Phase 1: convert + permute (both tensors in one launch) ----------
// dst[m][r*1024 + k] = (bf16) src[r][m][k].  8 elems/thread, 16B stores.
__global__ __launch_bounds__(256) void convert_permute2(
    const float* __restrict__ srcA, unsigned short* __restrict__ dstA,
    const float* __restrict__ srcB, unsigned short* __restrict__ dstB,
    int blocks_per_tensor) {
    const float* src = srcA;
    unsigned short* dst = dstA;
    int b = blockIdx.x;
    if (b >= blocks_per_tensor) { b -= blocks_per_tensor; src = srcB; dst = dstB; }
    size_t t = (size_t)b * 256 + threadIdx.x;
    size_t e = t * 8;  // flat element index in [R, M, K_LOCAL]
    int r = (int)(e >> 22);            // / (4096*1024)
    int rem = (int)(e & 0x3FFFFFu);
    int m = rem >> 10;
    int k = rem & 1023;
    float4 v0 = *(const float4*)(src + e);
    float4 v1 = *(const float4*)(src + e + 4);
    ushort4 o0, o1;
    o0.x = f2bf(v0.x); o0.y = f2bf(v0.y); o0.z = f2bf(v0.z); o0.w = f2bf(v0.w);
    o1.x = f2bf(v1.x); o1.y = f2bf(v1.y); o1.z = f2bf(v1.z); o1.w = f2bf(v1.w);
    unsigned short* p = dst + (size_t)m * K_DIM + r * K_LOCAL + k;
    *(ushort4*)p = o0;
    *(ushort4*)(p + 4) = o1;
}

// ---------- Phase 2: bf16 MFMA GEMM ----------
__device__ __forceinline__ void async_copy16(const unsigned short* g, unsigned short* l) {
    __builtin_amdgcn_global_load_lds(
        (const __attribute__((address_space(1))) void*)g,
        (__attribute__((address_space(3))) void*)l,
        16, 0, 0);
}

__global__ __launch_bounds__(256) void gemm_bf16(
    const unsigned short* __restrict__ A,  // [M, K] bf16
    const unsigned short* __restrict__ B,  // [N, K] bf16
    float* __restrict__ C) {               // [M, N] fp32
    __shared__ __align__(16) unsigned short As[128 * 64];
    __shared__ __align__(16) unsigned short Bs[128 * 64];

    const int tid = threadIdx.x;
    const int lane = tid & 63;
    const int wave = tid >> 6;
    const int wm = (wave >> 1) * 64;   // wave row offset in 128x128 tile
    const int wn = (wave & 1) * 64;    // wave col offset
    const int l15 = lane & 15;
    const int l4 = lane >> 4;
    const int bm0 = blockIdx.y * 128;
    const int bn0 = blockIdx.x * 128;

    // Staging: LDS chunk cc = p*256 + tid is (row = cc>>3, pos = cc&7).
    // XOR swizzle: chunk (row,pos) holds global 16B chunk col8 = pos ^ (row&7).
    // (Permutation stays inside the row's 128B segment -> coalescing intact.)
    const unsigned short* ga[4];
    const unsigned short* gb[4];
    int lo[4];
#pragma unroll
    for (int p = 0; p < 4; ++p) {
        int cc = p * 256 + tid;
        int row = cc >> 3;
        int pos = cc & 7;
        int col = (pos ^ (row & 7)) * 8;
        ga[p] = A + (size_t)(bm0 + row) * K_DIM + col;
        gb[p] = B + (size_t)(bn0 + row) * K_DIM + col;
        lo[p] = cc * 8;
    }

    // Fragment read: row_local = wm|wn + l15 + 16i (== l15&7 mod 8), chunk c = l4 + 4*ks.
    // Swizzled element offset within row: (c ^ (l15&7)) * 8.
    const int swz0 = ((l4 + 0) ^ (l15 & 7)) * 8;  // ks = 0
    const int swz1 = ((l4 + 4) ^ (l15 & 7)) * 8;  // ks = 1
    const int a_row = (wm + l15) * 64;
    const int b_row = (wn + l15) * 64;

    f32x4 acc[4][4] = {};

    for (int kt = 0; kt < K_DIM; kt += 64) {
#pragma unroll
        for (int p = 0; p < 4; ++p) {
            async_copy16(ga[p] + kt, &As[lo[p]]);
            async_copy16(gb[p] + kt, &Bs[lo[p]]);
        }
        __syncthreads();
#pragma unroll
        for (int ks = 0; ks < 2; ++ks) {
            const int swz = ks ? swz1 : swz0;
            bf16x8 af[4], bfr[4];
#pragma unroll
            for (int i = 0; i < 4; ++i)
                af[i] = *(const bf16x8*)&As[a_row + i * 16 * 64 + swz];
#pragma unroll
            for (int j = 0; j < 4; ++j)
                bfr[j] = *(const bf16x8*)&Bs[b_row + j * 16 * 64 + swz];
#pragma unroll
            for (int i = 0; i < 4; ++i)
#pragma unroll
                for (int j = 0; j < 4; ++j)
                    acc[i][j] = __builtin_amdgcn_mfma_f32_16x16x32_bf16(
                        af[i], bfr[j], acc[i][j], 0, 0, 0);
        }
        __syncthreads();
    }

    // epilogue: C/D layout col = lane&15, row = (lane>>4)*4 + reg
#pragma unroll
    for (int i = 0; i < 4; ++i) {
        int row0 = bm0 + wm + i * 16 + l4 * 4;
#pragma unroll
        for (int j = 0; j < 4; ++j) {
            int col = bn0 + wn + j * 16 + l15;
#pragma unroll
            for (int r = 0; r < 4; ++r)
                C[(size_t)(row0 + r) * N_DIM + col] = acc[i][j][r];
        }
    }
}

// ---------- Fallback (ws too small): naive fp32 tiled GEMM on original layout ----------
__global__ void gemm_naive(const float* __restrict__ A, const float* __restrict__ B,
                           float* __restrict__ C) {
    __shared__ float As[16][17];
    __shared__ float Bs[16][17];
    int tx = threadIdx.x, ty = threadIdx.y;
    int m = blockIdx.y * 16 + ty;
    int n0 = blockIdx.x * 16;
    float accv = 0.f;
    for (int kt = 0; kt < K_DIM; kt += 16) {
        int r = kt >> 10;
        int k = (kt & 1023) + tx;
        As[ty][tx] = A[((size_t)r * M_DIM + m) * K_LOCAL + k];
        Bs[ty][tx] = B[((size_t)r * N_DIM + (n0 + ty)) * K_LOCAL + k];
        __syncthreads();
#pragma unroll
        for (int kk = 0; kk < 16; ++kk) accv += As[ty][kk] * Bs[tx][kk];
        __syncthreads();
    }
    C[(size_t)m * N_DIM + n0 + tx] = accv;
}

extern "C" void kernel_launch(void* const* d_in, const int* in_sizes, int n_in,
                              void* d_out, int out_size, void* d_ws, size_t ws_size,
                              hipStream_t stream) {
    const float* inp = (const float*)d_in[0];
    const float* wgt = (const float*)d_in[1];
    float* out = (float*)d_out;

    const size_t elems = (size_t)M_DIM * K_DIM;              // 33,554,432 per tensor
    const size_t need = 2 * elems * sizeof(unsigned short);  // 128 MiB

    if (ws_size >= need) {
        unsigned short* Abf = (unsigned short*)d_ws;
        unsigned short* Bbf = Abf + elems;
        const int bpt = (int)(elems / 8 / 256);   // 16384 blocks per tensor
        convert_permute2<<<bpt * 2, 256, 0, stream>>>(inp, Abf, wgt, Bbf, bpt);
        dim3 grid(N_DIM / 128, M_DIM / 128);      // 32 x 32
        gemm_bf16<<<grid, 256, 0, stream>>>(Abf, Bbf, out);
    } else {
        dim3 grid(N_DIM / 16, M_DIM / 16);
        dim3 block(16, 16);
        gemm_naive<<<grid, block, 0, stream>>>(inp, wgt, out);
    }
}

// Round 3
// 608.902 us; speedup vs baseline: 1.1212x; 1.0194x over previous
//
#include <hip/hip_runtime.h>
#include <cstdint>
#include <cstddef>

// C[4096,4096] = sum_r input[r] @ weight[r]^T  == GEMM M=N=4096, K=8192, fp32 out.
// Phase 1: fp32 -> bf16 LINEAR cast (keeps [R,M,K_LOCAL] layout; R3 change —
//          the old [M,K] permute scattered writes at 16KB stride, 1.5 TB/s).
// Phase 2: m97-recipe bf16 MFMA GEMM (128x128 tile, BK=64, global_load_lds w=16)
//          + XOR bank swizzle (R2: conflicts 1e8 -> 0), r-outer/k-inner loop.

#define M_DIM 4096
#define N_DIM 4096
#define K_DIM 8192
#define K_LOCAL 1024
#define RANKS 8

typedef __bf16 bf16x8 __attribute__((ext_vector_type(8)));
typedef float f32x4 __attribute__((ext_vector_type(4)));

__device__ __forceinline__ unsigned short f2bf(float f) {
    unsigned int u = __float_as_uint(f);
    unsigned int r = (u + 0x7fffu + ((u >> 16) & 1u)) >> 16;
    return (unsigned short)r;
}

// ---------- Phase 1: pure linear fp32 -> bf16 cast, 16 elems/thread ----------
__global__ __launch_bounds__(256) void convert_cast(
    const float* __restrict__ srcA, unsigned short* __restrict__ dstA,
    const float* __restrict__ srcB, unsigned short* __restrict__ dstB,
    int blocks_per_tensor) {
    const float* src = srcA;
    unsigned short* dst = dstA;
    int b = blockIdx.x;
    if (b >= blocks_per_tensor) { b -= blocks_per_tensor; src = srcB; dst = dstB; }
    size_t e = ((size_t)b * 256 + threadIdx.x) * 16;
    float4 v0 = *(const float4*)(src + e);
    float4 v1 = *(const float4*)(src + e + 4);
    float4 v2 = *(const float4*)(src + e + 8);
    float4 v3 = *(const float4*)(src + e + 12);
    ushort4 o0, o1, o2, o3;
    o0.x = f2bf(v0.x); o0.y = f2bf(v0.y); o0.z = f2bf(v0.z); o0.w = f2bf(v0.w);
    o1.x = f2bf(v1.x); o1.y = f2bf(v1.y); o1.z = f2bf(v1.z); o1.w = f2bf(v1.w);
    o2.x = f2bf(v2.x); o2.y = f2bf(v2.y); o2.z = f2bf(v2.z); o2.w = f2bf(v2.w);
    o3.x = f2bf(v3.x); o3.y = f2bf(v3.y); o3.z = f2bf(v3.z); o3.w = f2bf(v3.w);
    *(ushort4*)(dst + e) = o0;
    *(ushort4*)(dst + e + 4) = o1;
    *(ushort4*)(dst + e + 8) = o2;
    *(ushort4*)(dst + e + 12) = o3;
}

// ---------- Phase 2: bf16 MFMA GEMM over [R, rows, K_LOCAL] operands ----------
__device__ __forceinline__ void async_copy16(const unsigned short* g, unsigned short* l) {
    __builtin_amdgcn_global_load_lds(
        (const __attribute__((address_space(1))) void*)g,
        (__attribute__((address_space(3))) void*)l,
        16, 0, 0);
}

__global__ __launch_bounds__(256) void gemm_bf16(
    const unsigned short* __restrict__ A,  // [R, M, K_LOCAL] bf16
    const unsigned short* __restrict__ B,  // [R, N, K_LOCAL] bf16
    float* __restrict__ C) {               // [M, N] fp32
    __shared__ __align__(16) unsigned short As[128 * 64];
    __shared__ __align__(16) unsigned short Bs[128 * 64];

    const int tid = threadIdx.x;
    const int lane = tid & 63;
    const int wave = tid >> 6;
    const int wm = (wave >> 1) * 64;
    const int wn = (wave & 1) * 64;
    const int l15 = lane & 15;
    const int l4 = lane >> 4;
    const int bm0 = blockIdx.y * 128;
    const int bn0 = blockIdx.x * 128;

    // Staging: LDS chunk cc = p*256 + tid is (row = cc>>3, pos = cc&7).
    // XOR swizzle: chunk (row,pos) holds global 16B chunk col8 = pos ^ (row&7).
    const unsigned short* ga[4];
    const unsigned short* gb[4];
    int lo[4];
#pragma unroll
    for (int p = 0; p < 4; ++p) {
        int cc = p * 256 + tid;
        int row = cc >> 3;
        int pos = cc & 7;
        int col = (pos ^ (row & 7)) * 8;
        ga[p] = A + (size_t)(bm0 + row) * K_LOCAL + col;
        gb[p] = B + (size_t)(bn0 + row) * K_LOCAL + col;
        lo[p] = cc * 8;
    }

    const int swz0 = ((l4 + 0) ^ (l15 & 7)) * 8;  // ks = 0
    const int swz1 = ((l4 + 4) ^ (l15 & 7)) * 8;  // ks = 1
    const int a_row = (wm + l15) * 64;
    const int b_row = (wn + l15) * 64;

    f32x4 acc[4][4] = {};

    for (int r = 0; r < RANKS; ++r) {
        const size_t roff = (size_t)r * (M_DIM * (size_t)K_LOCAL);
        for (int kl = 0; kl < K_LOCAL; kl += 64) {
#pragma unroll
            for (int p = 0; p < 4; ++p) {
                async_copy16(ga[p] + roff + kl, &As[lo[p]]);
                async_copy16(gb[p] + roff + kl, &Bs[lo[p]]);
            }
            __syncthreads();
#pragma unroll
            for (int ks = 0; ks < 2; ++ks) {
                const int swz = ks ? swz1 : swz0;
                bf16x8 af[4], bfr[4];
#pragma unroll
                for (int i = 0; i < 4; ++i)
                    af[i] = *(const bf16x8*)&As[a_row + i * 16 * 64 + swz];
#pragma unroll
                for (int j = 0; j < 4; ++j)
                    bfr[j] = *(const bf16x8*)&Bs[b_row + j * 16 * 64 + swz];
#pragma unroll
                for (int i = 0; i < 4; ++i)
#pragma unroll
                    for (int j = 0; j < 4; ++j)
                        acc[i][j] = __builtin_amdgcn_mfma_f32_16x16x32_bf16(
                            af[i], bfr[j], acc[i][j], 0, 0, 0);
            }
            __syncthreads();
        }
    }

    // epilogue: C/D layout col = lane&15, row = (lane>>4)*4 + reg
#pragma unroll
    for (int i = 0; i < 4; ++i) {
        int row0 = bm0 + wm + i * 16 + l4 * 4;
#pragma unroll
        for (int j = 0; j < 4; ++j) {
            int col = bn0 + wn + j * 16 + l15;
#pragma unroll
            for (int r = 0; r < 4; ++r)
                C[(size_t)(row0 + r) * N_DIM + col] = acc[i][j][r];
        }
    }
}

// ---------- Fallback (ws too small): naive fp32 tiled GEMM ----------
__global__ void gemm_naive(const float* __restrict__ A, const float* __restrict__ B,
                           float* __restrict__ C) {
    __shared__ float As[16][17];
    __shared__ float Bs[16][17];
    int tx = threadIdx.x, ty = threadIdx.y;
    int m = blockIdx.y * 16 + ty;
    int n0 = blockIdx.x * 16;
    float accv = 0.f;
    for (int kt = 0; kt < K_DIM; kt += 16) {
        int r = kt >> 10;
        int k = (kt & 1023) + tx;
        As[ty][tx] = A[((size_t)r * M_DIM + m) * K_LOCAL + k];
        Bs[ty][tx] = B[((size_t)r * N_DIM + (n0 + ty)) * K_LOCAL + k];
        __syncthreads();
#pragma unroll
        for (int kk = 0; kk < 16; ++kk) accv += As[ty][kk] * Bs[tx][kk];
        __syncthreads();
    }
    C[(size_t)m * N_DIM + n0 + tx] = accv;
}

extern "C" void kernel_launch(void* const* d_in, const int* in_sizes, int n_in,
                              void* d_out, int out_size, void* d_ws, size_t ws_size,
                              hipStream_t stream) {
    const float* inp = (const float*)d_in[0];
    const float* wgt = (const float*)d_in[1];
    float* out = (float*)d_out;

    const size_t elems = (size_t)M_DIM * K_DIM;              // 33,554,432 per tensor
    const size_t need = 2 * elems * sizeof(unsigned short);  // 128 MiB

    if (ws_size >= need) {
        unsigned short* Abf = (unsigned short*)d_ws;
        unsigned short* Bbf = Abf + elems;
        const int bpt = (int)(elems / 16 / 256);  // 8192 blocks per tensor
        convert_cast<<<bpt * 2, 256, 0, stream>>>(inp, Abf, wgt, Bbf, bpt);
        dim3 grid(N_DIM / 128, M_DIM / 128);      // 32 x 32
        gemm_bf16<<<grid, 256, 0, stream>>>(Abf, Bbf, out);
    } else {
        dim3 grid(N_DIM / 16, M_DIM / 16);
        dim3 block(16, 16);
        gemm_naive<<<grid, block, 0, stream>>>(inp, wgt, out);
    }
}

// Round 5
// 538.987 us; speedup vs baseline: 1.2667x; 1.1297x over previous
//
#include <hip/hip_runtime.h>
#include <cstdint>
#include <cstddef>

// C[4096,4096] = sum_r input[r] @ weight[r]^T  == GEMM M=N=4096, K=8192, fp32 out.
// Phase 1: fp32 -> bf16 linear cast (instruction-coalesced, nontemporal reads).
// Phase 2: m97-recipe bf16 MFMA GEMM (128x128 tile, BK=64, global_load_lds w=16)
//          + XOR bank swizzle (R2: conflicts 1e8 -> 0)
//          + XCD-aware 2x2 supertile swizzle (R4: L2 locality, FETCH 355->~230MB).

#define M_DIM 4096
#define N_DIM 4096
#define K_DIM 8192
#define K_LOCAL 1024
#define RANKS 8

typedef __bf16 bf16x8 __attribute__((ext_vector_type(8)));
typedef float f32x4 __attribute__((ext_vector_type(4)));

__device__ __forceinline__ unsigned short f2bf(float f) {
    unsigned int u = __float_as_uint(f);
    unsigned int r = (u + 0x7fffu + ((u >> 16) & 1u)) >> 16;
    return (unsigned short)r;
}

// ---------- Phase 1: linear fp32 -> bf16 cast ----------
// Per-instruction lane-contiguous: load f32x4 (16B/lane, nontemporal — src is
// dead after the cast; keep L2/L3 clean for the gemm), store ushort4 (8B/lane).
__global__ __launch_bounds__(256) void convert_cast(
    const float* __restrict__ srcA, unsigned short* __restrict__ dstA,
    const float* __restrict__ srcB, unsigned short* __restrict__ dstB,
    int blocks_per_tensor) {
    const float* src = srcA;
    unsigned short* dst = dstA;
    int b = blockIdx.x;
    if (b >= blocks_per_tensor) { b -= blocks_per_tensor; src = srcB; dst = dstB; }
    size_t base = (size_t)b * 4096 + threadIdx.x * 4;
#pragma unroll
    for (int i = 0; i < 4; ++i) {
        size_t e = base + i * 1024;
        f32x4 v = __builtin_nontemporal_load((const f32x4*)(src + e));
        ushort4 o;
        o.x = f2bf(v.x); o.y = f2bf(v.y); o.z = f2bf(v.z); o.w = f2bf(v.w);
        *(ushort4*)(dst + e) = o;
    }
}

// ---------- Phase 2: bf16 MFMA GEMM over [R, rows, K_LOCAL] operands ----------
__device__ __forceinline__ void async_copy16(const unsigned short* g, unsigned short* l) {
    __builtin_amdgcn_global_load_lds(
        (const __attribute__((address_space(1))) void*)g,
        (__attribute__((address_space(3))) void*)l,
        16, 0, 0);
}

__global__ __launch_bounds__(256) void gemm_bf16(
    const unsigned short* __restrict__ A,  // [R, M, K_LOCAL] bf16
    const unsigned short* __restrict__ B,  // [R, N, K_LOCAL] bf16
    float* __restrict__ C) {               // [M, N] fp32
    __shared__ __align__(16) unsigned short As[128 * 64];
    __shared__ __align__(16) unsigned short Bs[128 * 64];

    const int tid = threadIdx.x;
    const int lane = tid & 63;
    const int wave = tid >> 6;
    const int wm = (wave >> 1) * 64;
    const int wn = (wave & 1) * 64;
    const int l15 = lane & 15;
    const int l4 = lane >> 4;

    // XCD-aware supertile swizzle: dispatch assumed round-robin (xcd = bid & 7).
    // Each XCD gets 2x2-block supertiles -> 4 co-resident blocks share
    // 2 A-strips + 2 B-strips in its 4MB L2.
    const int bid = blockIdx.x;            // 0..1023
    const int xcd = bid & 7;
    const int q = bid >> 3;                // 0..127
    const int st = (q >> 2) * 8 + xcd;     // supertile 0..255 (16x16 grid)
    const int pos = q & 3;
    const int bm0 = ((st >> 4) * 2 + (pos >> 1)) * 128;
    const int bn0 = ((st & 15) * 2 + (pos & 1)) * 128;

    // Staging: LDS chunk cc = p*256 + tid is (row = cc>>3, pos = cc&7).
    // XOR swizzle: chunk (row,pos) holds global 16B chunk col8 = pos ^ (row&7).
    const unsigned short* ga[4];
    const unsigned short* gb[4];
    int lo[4];
#pragma unroll
    for (int p = 0; p < 4; ++p) {
        int cc = p * 256 + tid;
        int row = cc >> 3;
        int cpos = cc & 7;
        int col = (cpos ^ (row & 7)) * 8;
        ga[p] = A + (size_t)(bm0 + row) * K_LOCAL + col;
        gb[p] = B + (size_t)(bn0 + row) * K_LOCAL + col;
        lo[p] = cc * 8;
    }

    const int swz0 = ((l4 + 0) ^ (l15 & 7)) * 8;  // ks = 0
    const int swz1 = ((l4 + 4) ^ (l15 & 7)) * 8;  // ks = 1
    const int a_row = (wm + l15) * 64;
    const int b_row = (wn + l15) * 64;

    f32x4 acc[4][4] = {};

    for (int r = 0; r < RANKS; ++r) {
        const size_t roff = (size_t)r * (M_DIM * (size_t)K_LOCAL);
        for (int kl = 0; kl < K_LOCAL; kl += 64) {
#pragma unroll
            for (int p = 0; p < 4; ++p) {
                async_copy16(ga[p] + roff + kl, &As[lo[p]]);
                async_copy16(gb[p] + roff + kl, &Bs[lo[p]]);
            }
            __syncthreads();
#pragma unroll
            for (int ks = 0; ks < 2; ++ks) {
                const int swz = ks ? swz1 : swz0;
                bf16x8 af[4], bfr[4];
#pragma unroll
                for (int i = 0; i < 4; ++i)
                    af[i] = *(const bf16x8*)&As[a_row + i * 16 * 64 + swz];
#pragma unroll
                for (int j = 0; j < 4; ++j)
                    bfr[j] = *(const bf16x8*)&Bs[b_row + j * 16 * 64 + swz];
#pragma unroll
                for (int i = 0; i < 4; ++i)
#pragma unroll
                    for (int j = 0; j < 4; ++j)
                        acc[i][j] = __builtin_amdgcn_mfma_f32_16x16x32_bf16(
                            af[i], bfr[j], acc[i][j], 0, 0, 0);
            }
            __syncthreads();
        }
    }

    // epilogue: C/D layout col = lane&15, row = (lane>>4)*4 + reg
#pragma unroll
    for (int i = 0; i < 4; ++i) {
        int row0 = bm0 + wm + i * 16 + l4 * 4;
#pragma unroll
        for (int j = 0; j < 4; ++j) {
            int col = bn0 + wn + j * 16 + l15;
#pragma unroll
            for (int r = 0; r < 4; ++r)
                C[(size_t)(row0 + r) * N_DIM + col] = acc[i][j][r];
        }
    }
}

// ---------- Fallback (ws too small): naive fp32 tiled GEMM ----------
__global__ void gemm_naive(const float* __restrict__ A, const float* __restrict__ B,
                           float* __restrict__ C) {
    __shared__ float As[16][17];
    __shared__ float Bs[16][17];
    int tx = threadIdx.x, ty = threadIdx.y;
    int m = blockIdx.y * 16 + ty;
    int n0 = blockIdx.x * 16;
    float accv = 0.f;
    for (int kt = 0; kt < K_DIM; kt += 16) {
        int r = kt >> 10;
        int k = (kt & 1023) + tx;
        As[ty][tx] = A[((size_t)r * M_DIM + m) * K_LOCAL + k];
        Bs[ty][tx] = B[((size_t)r * N_DIM + (n0 + ty)) * K_LOCAL + k];
        __syncthreads();
#pragma unroll
        for (int kk = 0; kk < 16; ++kk) accv += As[ty][kk] * Bs[tx][kk];
        __syncthreads();
    }
    C[(size_t)m * N_DIM + n0 + tx] = accv;
}

extern "C" void kernel_launch(void* const* d_in, const int* in_sizes, int n_in,
                              void* d_out, int out_size, void* d_ws, size_t ws_size,
                              hipStream_t stream) {
    const float* inp = (const float*)d_in[0];
    const float* wgt = (const float*)d_in[1];
    float* out = (float*)d_out;

    const size_t elems = (size_t)M_DIM * K_DIM;              // 33,554,432 per tensor
    const size_t need = 2 * elems * sizeof(unsigned short);  // 128 MiB

    if (ws_size >= need) {
        unsigned short* Abf = (unsigned short*)d_ws;
        unsigned short* Bbf = Abf + elems;
        const int bpt = (int)(elems / 4096);      // 8192 blocks per tensor
        convert_cast<<<bpt * 2, 256, 0, stream>>>(inp, Abf, wgt, Bbf, bpt);
        gemm_bf16<<<1024, 256, 0, stream>>>(Abf, Bbf, out);
    } else {
        dim3 grid(N_DIM / 16, M_DIM / 16);
        dim3 block(16, 16);
        gemm_naive<<<grid, block, 0, stream>>>(inp, wgt, out);
    }
}